// Round 7
// baseline (231.668 us; speedup 1.0000x reference)
//
#include <hip/hip_runtime.h>

#define B 4
#define C 256
#define CI 128
#define NPIX 3136      // 56*56 = 49 * 64
#define BN_EPS_F 1e-5f
#define INVN (1.0f / 3136.0f)

typedef float f4 __attribute__((ext_vector_type(4)));
typedef float f32x4 __attribute__((ext_vector_type(4)));
typedef short short8 __attribute__((ext_vector_type(8)));
typedef short short4v __attribute__((ext_vector_type(4)));
typedef unsigned int u32;
typedef u32 u32x4 __attribute__((ext_vector_type(4)));

__device__ inline short f2bf(float f) {
    u32 u = __builtin_bit_cast(u32, f);
    u32 r = (u + 0x7FFFu + ((u >> 16) & 1u)) >> 16;
    return (short)r;
}
__device__ inline float bf2f(short v) {
    u32 u = ((u32)(unsigned short)v) << 16;
    return __builtin_bit_cast(float, u);
}
__device__ inline u32 pk2(float a, float b) {
    return (u32)(unsigned short)f2bf(a) | ((u32)(unsigned short)f2bf(b) << 16);
}
__device__ inline short8 pack8(f4 v0, f4 v1) {
    u32x4 u = { pk2(v0[0], v0[1]), pk2(v0[2], v0[3]), pk2(v1[0], v1[1]), pk2(v1[2], v1[3]) };
    return __builtin_bit_cast(short8, u);
}
// XOR-swizzled byte offset into a [64][256] bf16 LDS tile (16B-block swizzle,
// breaks the 512B-row-stride 16-way bank conflict; bijective per row).
__device__ inline int hoff(int row, int col) {
    return ((row * C + col) * 2) ^ ((row & 7) << 4);
}

// ================= front: ALL x+weights-only work in ONE launch =================
// blocks [0,784): prep    — xT[b][n][c]=bf16(x), spart rowsum partials
// blocks [784,800): xxt   — Gbf[b] = bf16(x x^T), full K, fp32->bf16 on the fly
// blocks [800,816): lmat  — Lbf = bf16(diag(inv) wrec Wg)
// blocks [816,832): rmat  — Rtbf = bf16(Wtheta^T Wphi) = R^T
// block 832: vec          — p, tg, wt, consts, bnc
__global__ __launch_bounds__(256) void front_kernel(
        const float* __restrict__ x,
        const float* __restrict__ wrec, const float* __restrict__ wg,
        const float* __restrict__ wphi, const float* __restrict__ wtheta,
        const float* __restrict__ gamma, const float* __restrict__ var,
        const float* __restrict__ bg, const float* __restrict__ bphi,
        const float* __restrict__ btheta, const float* __restrict__ brec,
        const float* __restrict__ beta, const float* __restrict__ mean,
        short* __restrict__ xT, float* __restrict__ spart,
        short* __restrict__ Lbf, short* __restrict__ Rtbf, short* __restrict__ Gbf,
        float* __restrict__ p, float* __restrict__ tg, float* __restrict__ wt,
        float* __restrict__ consts, float* __restrict__ bnc) {
    __shared__ char smem[2 * 64 * 68 * 4];   // 34816 B, unioned across paths
    int bid = blockIdx.x;
    int t = threadIdx.x;

    if (bid < 784) {
        // ---------------- prep ----------------
        int nb = bid % 49, cb = (bid / 49) & 3, b = bid / 196;
        int n0 = nb * 64, c0 = cb * 64;
        short (*lds)[65] = (short(*)[65])smem;
        int nf = (t & 15) * 4;
        int cr = t >> 4;
        float psum[4];
#pragma unroll
        for (int it = 0; it < 4; ++it) {
            int c = cr + 16 * it;
            f4 v = *(const f4*)&x[((size_t)(b * C + c0 + c)) * NPIX + n0 + nf];
            float ps = 0.f;
#pragma unroll
            for (int i = 0; i < 4; ++i) { lds[nf + i][c] = f2bf(v[i]); ps += v[i]; }
            psum[it] = ps;
        }
#pragma unroll
        for (int it = 0; it < 4; ++it) {
            float ps = psum[it];
#pragma unroll
            for (int m = 8; m >= 1; m >>= 1) ps += __shfl_xor(ps, m, 64);
            if ((t & 15) == 0)
                spart[(size_t)(b * C + c0 + cr + 16 * it) * 49 + nb] = ps;
        }
        __syncthreads();
#pragma unroll
        for (int it = 0; it < 4; ++it) {
            int n = cr + 16 * it;
            short4v s4;
#pragma unroll
            for (int i = 0; i < 4; ++i) s4[i] = lds[n][nf + i];
            *(short4v*)&xT[((size_t)b * NPIX + n0 + n) * C + c0 + nf] = s4;
        }
    } else if (bid < 800) {
        // ---------------- xxt (full K, on-the-fly cvt) ----------------
        int q = bid - 784;
        int b = q >> 2, quad = q & 3;
        int lane = t & 63, wid = t >> 6;
        int ibase = (quad >> 1) * 128 + (wid >> 1) * 64;
        int jbase = (quad & 1) * 128 + (wid & 1) * 64;
        int lm = lane & 15, lk = (lane >> 4) * 8;
        const float* A0 = x + ((size_t)(b * C) + ibase + lm) * NPIX + lk;
        const float* B0 = x + ((size_t)(b * C) + jbase + lm) * NPIX + lk;
        f32x4 acc[4][4] = {};
        for (int k = 0; k < NPIX; k += 32) {
            short8 a[4], bv[4];
#pragma unroll
            for (int mi = 0; mi < 4; ++mi) {
                const float* ap = A0 + (size_t)mi * 16 * NPIX + k;
                a[mi] = pack8(*(const f4*)ap, *(const f4*)(ap + 4));
            }
#pragma unroll
            for (int nj = 0; nj < 4; ++nj) {
                const float* bp = B0 + (size_t)nj * 16 * NPIX + k;
                bv[nj] = pack8(*(const f4*)bp, *(const f4*)(bp + 4));
            }
#pragma unroll
            for (int mi = 0; mi < 4; ++mi)
#pragma unroll
                for (int nj = 0; nj < 4; ++nj)
                    acc[mi][nj] = __builtin_amdgcn_mfma_f32_16x16x32_bf16(a[mi], bv[nj], acc[mi][nj], 0, 0, 0);
        }
        short* Gb = Gbf + (size_t)b * C * C;
        int r0 = (lane >> 4) * 4;
#pragma unroll
        for (int mi = 0; mi < 4; ++mi)
#pragma unroll
            for (int r = 0; r < 4; ++r)
#pragma unroll
                for (int nj = 0; nj < 4; ++nj)
                    Gb[(ibase + mi * 16 + r0 + r) * C + jbase + nj * 16 + lm] = f2bf(acc[mi][nj][r]);
    } else if (bid < 832) {
        // ---------------- lmat / rmat ----------------
        bool isL = bid < 816;
        int bi = isL ? (bid - 800) : (bid - 816);
        int i0 = (bi >> 2) * 64, j0 = (bi & 3) * 64;
        float (*wl)[68] = (float(*)[68])smem;
        float (*xl)[68] = (float(*)[68])(smem + 64 * 68 * 4);
        int tx = t & 15, ty = t >> 4;
        float acc[4][4] = {};
        for (int k0 = 0; k0 < CI; k0 += 64) {
            __syncthreads();
            if (isL) {
#pragma unroll
                for (int l = 0; l < 4; ++l) {
                    int idx = t + l * 256;
                    int r = idx >> 4, c4 = (idx & 15) << 2;
                    *(f4*)&wl[r][c4] = *(const f4*)&wrec[(i0 + r) * CI + k0 + c4];
                    *(f4*)&xl[r][c4] = *(const f4*)&wg[(size_t)(k0 + r) * C + j0 + c4];
                }
            } else {
#pragma unroll
                for (int l = 0; l < 4; ++l) {
                    int idx = t + l * 256;
                    int jl = idx >> 4, cf4 = (idx & 15) << 2;
                    f4 v = *(const f4*)&wtheta[(size_t)(k0 + jl) * C + i0 + cf4];
#pragma unroll
                    for (int i = 0; i < 4; ++i) wl[cf4 + i][jl] = v[i];
                    *(f4*)&xl[jl][cf4] = *(const f4*)&wphi[(size_t)(k0 + jl) * C + j0 + cf4];
                }
            }
            __syncthreads();
            for (int kk = 0; kk < 64; kk += 4) {
                f4 a[4], bb[4];
#pragma unroll
                for (int i = 0; i < 4; ++i) a[i] = *(const f4*)&wl[ty + 16 * i][kk];
#pragma unroll
                for (int qq = 0; qq < 4; ++qq) bb[qq] = *(const f4*)&xl[kk + qq][tx * 4];
#pragma unroll
                for (int qq = 0; qq < 4; ++qq)
#pragma unroll
                    for (int i = 0; i < 4; ++i)
#pragma unroll
                        for (int j = 0; j < 4; ++j)
                            acc[i][j] += a[i][qq] * bb[qq][j];
            }
        }
        short* dst = isL ? Lbf : Rtbf;
#pragma unroll
        for (int i = 0; i < 4; ++i) {
            int r = i0 + ty + 16 * i;
            float scale = isL ? gamma[r] * rsqrtf(var[r] + BN_EPS_F) : 1.0f;
#pragma unroll
            for (int j = 0; j < 4; ++j)
                dst[r * C + j0 + tx * 4 + j] = f2bf(scale * acc[i][j]);
        }
    } else {
        // ---------------- vec ----------------
        float* red = (float*)smem;
        float acc_t = 0.f, acc_w = 0.f;
        for (int j = 0; j < CI; ++j) {
            acc_t = fmaf(wtheta[j * C + t], bphi[j], acc_t);
            acc_w = fmaf(wphi[j * C + t], btheta[j], acc_w);
        }
        float accp = 0.f;
#pragma unroll 4
        for (int j4 = 0; j4 < CI; j4 += 4) {
            f4 w = *(const f4*)&wrec[t * CI + j4];
            f4 b4 = *(const f4*)&bg[j4];
            accp += w[0] * b4[0] + w[1] * b4[1] + w[2] * b4[2] + w[3] * b4[3];
        }
        float inv = gamma[t] * rsqrtf(var[t] + BN_EPS_F);
        tg[t] = acc_t;
        wt[t] = acc_w;
        p[t] = inv * accp;
        bnc[t] = inv * brec[t] + beta[t] - mean[t] * inv;
        float cp = (t < CI) ? bphi[t] * btheta[t] : 0.f;
#pragma unroll
        for (int m = 32; m >= 1; m >>= 1) cp += __shfl_xor(cp, m, 64);
        if ((t & 63) == 0) red[t >> 6] = cp;
        __syncthreads();
        if (t == 0) consts[0] = red[0] + red[1] + red[2] + red[3];
    }
}

// ================= hw5: W5bf + bias5 via MFMA, 16 blocks =================
// block (it, b): o-strip = it*64.  phase1: H[o-strip][c] = Lbf . Gbf (G sym),
// bf16 into swizzled LDS.  phase2: W5 = H . Rt^T + rank-1; bias5 epilogue.
__global__ __launch_bounds__(256) void hw5_kernel(
        const short* __restrict__ Lbf, const short* __restrict__ Rtbf,
        const short* __restrict__ Gbf, const float* __restrict__ spart,
        const float* __restrict__ p, const float* __restrict__ tg,
        const float* __restrict__ wt, const float* __restrict__ consts,
        const float* __restrict__ bnc,
        short* __restrict__ W5bf, float* __restrict__ bias5) {
    int it = blockIdx.x, b = blockIdx.y;
    int o0 = it * 64;
    __shared__ char HlB[64 * C * 2];                    // 32 KB, swizzled
    __shared__ float sl[C], wtl[C], tgl[C], qarr[C];
    __shared__ float Lsp[4][64], biasp[4][64], LsS[64], redsw[4];
    int t = threadIdx.x, lane = t & 63, wid = t >> 6;
    int lm = lane & 15, lk = (lane >> 4) * 8;
    int r0 = (lane >> 4) * 4;

    // 1. stage sl (deterministic 49-partial sum), wtl, tgl
    {
        const float* sp = spart + (size_t)(b * C + t) * 49;
        float sv = 0.f;
        for (int i = 0; i < 49; ++i) sv += sp[i];
        sl[t] = sv; wtl[t] = wt[t]; tgl[t] = tg[t];
    }
    __syncthreads();

    // 2. phase1: per wave, H[o-strip 64][c-chunk 64] (K=256 over Gbf rows, G sym)
    {
        int cw = wid * 64;
        const short* Al = Lbf + (size_t)(o0 + lm) * C + lk;
        const short* Bg = Gbf + ((size_t)b * C + cw + lm) * C + lk;
        f32x4 hacc[4][4] = {};
        for (int k = 0; k < C; k += 32) {
            short8 a[4], bb[4];
#pragma unroll
            for (int mi = 0; mi < 4; ++mi) a[mi] = *(const short8*)(Al + (size_t)mi * 16 * C + k);
#pragma unroll
            for (int nj = 0; nj < 4; ++nj) bb[nj] = *(const short8*)(Bg + (size_t)nj * 16 * C + k);
#pragma unroll
            for (int mi = 0; mi < 4; ++mi)
#pragma unroll
                for (int nj = 0; nj < 4; ++nj)
                    hacc[mi][nj] = __builtin_amdgcn_mfma_f32_16x16x32_bf16(a[mi], bb[nj], hacc[mi][nj], 0, 0, 0);
        }
#pragma unroll
        for (int mi = 0; mi < 4; ++mi)
#pragma unroll
            for (int r = 0; r < 4; ++r)
#pragma unroll
                for (int nj = 0; nj < 4; ++nj) {
                    int ol = mi * 16 + r0 + r;
                    int cc = cw + nj * 16 + lm;
                    *(short*)(HlB + hoff(ol, cc)) = f2bf(hacc[mi][nj][r]);
                }
    }
    __syncthreads();

    // 3. sl-dependent VALU: qarr, Ls partials, biasH partials, swt
    {
        const short8* rr = (const short8*)(Rtbf + (size_t)t * C);
        float a = 0.f;
        for (int c8 = 0; c8 < 32; ++c8) {
            short8 v = rr[c8];
#pragma unroll
            for (int i = 0; i < 8; ++i) a += bf2f(v[i]) * sl[c8 * 8 + i];
        }
        qarr[t] = a;   // qarr[j] = sum_c s[c] R[c][j]
    }
    {
        int ol = t & 63, qq = t >> 6;
        const short8* lr = (const short8*)(Lbf + (size_t)(o0 + ol) * C + qq * 64);
        float a = 0.f;
        for (int c8 = 0; c8 < 8; ++c8) {
            short8 v = lr[c8];
#pragma unroll
            for (int i = 0; i < 8; ++i) a += bf2f(v[i]) * sl[qq * 64 + c8 * 8 + i];
        }
        Lsp[qq][ol] = a;
        float bh = 0.f;
        for (int c = 0; c < 64; ++c) {
            int cc = qq * 64 + c;
            bh += bf2f(*(const short*)(HlB + hoff(ol, cc))) * wtl[cc];
        }
        biasp[qq][ol] = bh;
    }
    {
        float part = sl[t] * wtl[t];
#pragma unroll
        for (int m = 32; m >= 1; m >>= 1) part += __shfl_xor(part, m, 64);
        if ((t & 63) == 0) redsw[t >> 6] = part;
    }
    __syncthreads();

    // 4. bias5 + LsS
    if (t < 64) {
        float ls = Lsp[0][t] + Lsp[1][t] + Lsp[2][t] + Lsp[3][t];
        LsS[t] = ls;
        float bh = biasp[0][t] + biasp[1][t] + biasp[2][t] + biasp[3][t];
        float swt = redsw[0] + redsw[1] + redsw[2] + redsw[3];
        int o = o0 + t;
        float po = p[o];
        bias5[b * C + o] = INVN * bh + INVN * swt * po
                         + consts[0] * (INVN * ls + po) + bnc[o];
    }
    __syncthreads();

    // 5. phase2: per wave, W5[o-strip 64][j-chunk 64] = H . Rt^T + rank-1
    {
        int jw = wid * 64;
        const short* Brt = Rtbf + (size_t)(jw + lm) * C + lk;
        f32x4 wacc[4][4] = {};
        for (int k = 0; k < C; k += 32) {
            short8 a[4], bb[4];
#pragma unroll
            for (int mi = 0; mi < 4; ++mi)
                a[mi] = *(const short8*)(HlB + hoff(mi * 16 + lm, k + lk));
#pragma unroll
            for (int nj = 0; nj < 4; ++nj)
                bb[nj] = *(const short8*)(Brt + (size_t)nj * 16 * C + k);
#pragma unroll
            for (int mi = 0; mi < 4; ++mi)
#pragma unroll
                for (int nj = 0; nj < 4; ++nj)
                    wacc[mi][nj] = __builtin_amdgcn_mfma_f32_16x16x32_bf16(a[mi], bb[nj], wacc[mi][nj], 0, 0, 0);
        }
        short* Wb = W5bf + (size_t)b * C * C;
#pragma unroll
        for (int mi = 0; mi < 4; ++mi) {
#pragma unroll
            for (int r = 0; r < 4; ++r) {
                int ol = mi * 16 + r0 + r;
                int o = o0 + ol;
                float po = p[o];
                float ls = LsS[ol];
#pragma unroll
                for (int nj = 0; nj < 4; ++nj) {
                    int j = jw + nj * 16 + lm;
                    float qj = INVN * qarr[j] + tgl[j];
                    float w5v = INVN * wacc[mi][nj][r] + po * qj + INVN * ls * tgl[j];
                    Wb[o * C + j] = f2bf(w5v);
                }
            }
        }
    }
}

// ================= final: out = W5 x + bias5 + x =================
__global__ __launch_bounds__(256) void final_mfma(const float* __restrict__ x,
                                                  const short* __restrict__ W5bf,
                                                  const short* __restrict__ xT,
                                                  const float* __restrict__ bias5,
                                                  float* __restrict__ out) {
    int b = blockIdx.y;
    int n0 = blockIdx.x * 64;
    int tid = threadIdx.x, lane = tid & 63, wid = tid >> 6;
    int obase = wid * 64;
    int lm = lane & 15, lk = (lane >> 4) * 8;
    const short* A0 = W5bf + ((size_t)(b * C) + obase + lm) * C + lk;
    const short* B0 = xT + ((size_t)b * NPIX + n0 + lm) * C + lk;
    f32x4 acc[4][4] = {};
#pragma unroll
    for (int k = 0; k < C; k += 32) {
        short8 a[4], bv[4];
#pragma unroll
        for (int mi = 0; mi < 4; ++mi) a[mi] = *(const short8*)(A0 + mi * 16 * C + k);
#pragma unroll
        for (int nj = 0; nj < 4; ++nj) bv[nj] = *(const short8*)(B0 + nj * 16 * C + k);
#pragma unroll
        for (int mi = 0; mi < 4; ++mi)
#pragma unroll
            for (int nj = 0; nj < 4; ++nj)
                acc[mi][nj] = __builtin_amdgcn_mfma_f32_16x16x32_bf16(a[mi], bv[nj], acc[mi][nj], 0, 0, 0);
    }
    int r0 = (lane >> 4) * 4;
#pragma unroll
    for (int mi = 0; mi < 4; ++mi) {
#pragma unroll
        for (int r = 0; r < 4; ++r) {
            int o = obase + mi * 16 + r0 + r;
            float bias = bias5[b * C + o];
            const float* xrow = x + ((size_t)(b * C + o)) * NPIX;
            float* orow = out + ((size_t)(b * C + o)) * NPIX;
#pragma unroll
            for (int nj = 0; nj < 4; ++nj) {
                int n = n0 + nj * 16 + lm;
                orow[n] = acc[mi][nj][r] + bias + xrow[n];
            }
        }
    }
}

extern "C" void kernel_launch(void* const* d_in, const int* in_sizes, int n_in,
                              void* d_out, int out_size, void* d_ws, size_t ws_size,
                              hipStream_t stream) {
    const float* x       = (const float*)d_in[0];
    const float* w_theta = (const float*)d_in[1];
    const float* b_theta = (const float*)d_in[2];
    const float* w_phi   = (const float*)d_in[3];
    const float* b_phi   = (const float*)d_in[4];
    const float* w_g     = (const float*)d_in[5];
    const float* b_g     = (const float*)d_in[6];
    const float* w_rec   = (const float*)d_in[7];
    const float* b_rec   = (const float*)d_in[8];
    const float* gamma   = (const float*)d_in[9];
    const float* beta    = (const float*)d_in[10];
    const float* mean    = (const float*)d_in[11];
    const float* var     = (const float*)d_in[12];
    float* out = (float*)d_out;

    char* wsb = (char*)d_ws;
    float* spart  = (float*)(wsb + 0);            // 4*256*49 f32 = 200704 B
    float* p      = (float*)(wsb + 204800);       // 1 KB
    float* tg     = (float*)(wsb + 205824);
    float* wt     = (float*)(wsb + 206848);
    float* bnc    = (float*)(wsb + 207872);
    float* consts = (float*)(wsb + 208896);
    float* bias5  = (float*)(wsb + 212992);       // 4 KB
    short* Lbf    = (short*)(wsb + 262144);       // 128 KB
    short* Rtbf   = (short*)(wsb + 393216);       // 128 KB
    short* Gbf    = (short*)(wsb + 524288);       // 512 KB
    short* W5bf   = (short*)(wsb + 1048576);      // 512 KB
    short* xT     = (short*)(wsb + 2097152);      // 6.42 MB

    front_kernel<<<dim3(833), dim3(256), 0, stream>>>(
        x, w_rec, w_g, w_phi, w_theta, gamma, var, b_g, b_phi, b_theta,
        b_rec, beta, mean, xT, spart, Lbf, Rtbf, Gbf, p, tg, wt, consts, bnc);
    hw5_kernel<<<dim3(4, B), dim3(256), 0, stream>>>(
        Lbf, Rtbf, Gbf, spart, p, tg, wt, consts, bnc, W5bf, bias5);
    final_mfma<<<dim3(NPIX / 64, B), dim3(256), 0, stream>>>(x, W5bf, xT, bias5, out);
}

// Round 8
// 166.194 us; speedup vs baseline: 1.3940x; 1.3940x over previous
//
#include <hip/hip_runtime.h>

#define B 4
#define C 256
#define CI 128
#define NPIX 3136      // 56*56 = 49 * 64
#define BN_EPS_F 1e-5f
#define INVN (1.0f / 3136.0f)

typedef float f4 __attribute__((ext_vector_type(4)));
typedef float f32x4 __attribute__((ext_vector_type(4)));
typedef short short8 __attribute__((ext_vector_type(8)));
typedef short short4v __attribute__((ext_vector_type(4)));
typedef unsigned int u32;
typedef u32 u32x4 __attribute__((ext_vector_type(4)));

__device__ inline short f2bf(float f) {
    u32 u = __builtin_bit_cast(u32, f);
    u32 r = (u + 0x7FFFu + ((u >> 16) & 1u)) >> 16;
    return (short)r;
}
__device__ inline float bf2f(short v) {
    u32 u = ((u32)(unsigned short)v) << 16;
    return __builtin_bit_cast(float, u);
}
__device__ inline u32 pk2(float a, float b) {
    return (u32)(unsigned short)f2bf(a) | ((u32)(unsigned short)f2bf(b) << 16);
}
__device__ inline short8 pack8(f4 v0, f4 v1) {
    u32x4 u = { pk2(v0[0], v0[1]), pk2(v0[2], v0[3]), pk2(v1[0], v1[1]), pk2(v1[2], v1[3]) };
    return __builtin_bit_cast(short8, u);
}

// ---- prep: xbf[b][c][n], xT[b][n][c] (bf16), spart rowsum partials. grid (49,4,B) ----
__global__ __launch_bounds__(256) void prep_kernel(const float* __restrict__ x,
                                                   short* __restrict__ xbf,
                                                   short* __restrict__ xT,
                                                   float* __restrict__ spart) {
    int b = blockIdx.z, c0 = blockIdx.y * 64, nb = blockIdx.x, n0 = nb * 64;
    __shared__ short lds[64][65];   // [n_local][c_local]
    int t = threadIdx.x;
    int nf = (t & 15) * 4;
    int cr = t >> 4;
    float psum[4];
#pragma unroll
    for (int it = 0; it < 4; ++it) {
        int c = cr + 16 * it;
        f4 v = *(const f4*)&x[((size_t)(b * C + c0 + c)) * NPIX + n0 + nf];
        short4v s4;
        float ps = 0.f;
#pragma unroll
        for (int i = 0; i < 4; ++i) { s4[i] = f2bf(v[i]); ps += v[i]; }
        psum[it] = ps;
        *(short4v*)&xbf[((size_t)(b * C + c0 + c)) * NPIX + n0 + nf] = s4;
#pragma unroll
        for (int i = 0; i < 4; ++i) lds[nf + i][c] = s4[i];
    }
#pragma unroll
    for (int it = 0; it < 4; ++it) {
        float ps = psum[it];
#pragma unroll
        for (int m = 8; m >= 1; m >>= 1) ps += __shfl_xor(ps, m, 64);
        if ((t & 15) == 0)
            spart[(size_t)(b * C + c0 + cr + 16 * it) * 49 + nb] = ps;
    }
    __syncthreads();
#pragma unroll
    for (int it = 0; it < 4; ++it) {
        int n = cr + 16 * it;
        short4v s4;
#pragma unroll
        for (int i = 0; i < 4; ++i) s4[i] = lds[n][nf + i];
        *(short4v*)&xT[((size_t)b * NPIX + n0 + n) * C + c0 + nf] = s4;
    }
}

// ---- xxt: Gbf[b] = bf16(x x^T). grid (4,4,B), 512t: 4 subtiles x 2 K-chunks ----
__global__ __launch_bounds__(512) void xxt_kernel(const short* __restrict__ xbf,
                                                  short* __restrict__ Gbf) {
    __shared__ float gred[4][32][33];   // 16.9 KB: kc=0 partials
    int b = blockIdx.z;
    int t = threadIdx.x, lane = t & 63, wid = t >> 6;
    int sub = wid & 3, kc = wid >> 2;
    int ibase = blockIdx.y * 64 + (sub >> 1) * 32;
    int jbase = blockIdx.x * 64 + (sub & 1) * 32;
    int lm = lane & 15, lk = (lane >> 4) * 8, r0 = (lane >> 4) * 4;
    const short* A0 = xbf + ((size_t)(b * C) + ibase + lm) * NPIX;
    const short* B0 = xbf + ((size_t)(b * C) + jbase + lm) * NPIX;
    f32x4 acc[2][2] = {};
    int k0 = kc * 1568, k1 = k0 + 1568;   // 49 steps of 32
    for (int k = k0; k < k1; k += 32) {
        short8 av[2], bv[2];
#pragma unroll
        for (int mi = 0; mi < 2; ++mi) av[mi] = *(const short8*)(A0 + (size_t)mi * 16 * NPIX + k + lk);
#pragma unroll
        for (int nj = 0; nj < 2; ++nj) bv[nj] = *(const short8*)(B0 + (size_t)nj * 16 * NPIX + k + lk);
#pragma unroll
        for (int mi = 0; mi < 2; ++mi)
#pragma unroll
            for (int nj = 0; nj < 2; ++nj)
                acc[mi][nj] = __builtin_amdgcn_mfma_f32_16x16x32_bf16(av[mi], bv[nj], acc[mi][nj], 0, 0, 0);
    }
    if (kc == 0) {
#pragma unroll
        for (int mi = 0; mi < 2; ++mi)
#pragma unroll
            for (int nj = 0; nj < 2; ++nj)
#pragma unroll
                for (int r = 0; r < 4; ++r)
                    gred[sub][mi * 16 + r0 + r][nj * 16 + lm] = acc[mi][nj][r];
    }
    __syncthreads();
    if (kc == 1) {
        short* Gb = Gbf + (size_t)b * C * C;
#pragma unroll
        for (int mi = 0; mi < 2; ++mi)
#pragma unroll
            for (int nj = 0; nj < 2; ++nj)
#pragma unroll
                for (int r = 0; r < 4; ++r) {
                    float v = acc[mi][nj][r] + gred[sub][mi * 16 + r0 + r][nj * 16 + lm];
                    Gb[(ibase + mi * 16 + r0 + r) * C + jbase + nj * 16 + lm] = f2bf(v);
                }
    }
}

// ---- middle: whole weight chain. grid (B), 512t (8 waves), dyn LDS 136 KB ----
// phases: 0a/0b/0c vectors; A: Ut=(G·Wφᵀ)ᵀ; B: T2t=(Wg·U)ᵀ; C: T3=wrec·T2;
// stage WθT; bias5; D: T4=T3·Wθ + rank-1 epilogue → W5bf.
__global__ __launch_bounds__(512) void middle_kernel(
        const short* __restrict__ Gbf, const float* __restrict__ spart,
        const float* __restrict__ wrec, const float* __restrict__ wg,
        const float* __restrict__ wphi, const float* __restrict__ wtheta,
        const float* __restrict__ gamma, const float* __restrict__ var,
        const float* __restrict__ bg, const float* __restrict__ bphi,
        const float* __restrict__ btheta, const float* __restrict__ brec,
        const float* __restrict__ beta, const float* __restrict__ mean,
        short* __restrict__ W5bf, float* __restrict__ bias5) {
    extern __shared__ char dyn[];
    short* buf1 = (short*)dyn;            // Ut[128][264] then T3[256][136]  (69632 B)
    short* buf2 = (short*)(dyn + 69632);  // T2t[128][136] then WθT[256][136] (69632 B)
    __shared__ float sl[C], invL[C], wtl[C], tgl[C], pv[C], qarr[C], Ls[C];
    __shared__ float uu[CI], vv[CI], scal[2];   // scal[0]=bφ·bθ, scal[1]=s·wt

    int b = blockIdx.x;
    int t = threadIdx.x, lane = t & 63, wid = t >> 6;
    int lm = lane & 15, lk = (lane >> 4) * 8, r0q = (lane >> 4) * 4;

    // ---- 0a ----
    if (t < 256) {
        const float* sp = spart + (size_t)(b * C + t) * 49;
        float sv = 0.f;
        for (int i = 0; i < 49; ++i) sv += sp[i];
        sl[t] = sv;
        float iv = gamma[t] * rsqrtf(var[t] + BN_EPS_F);
        invL[t] = iv;
        float a = 0.f;
#pragma unroll 4
        for (int j4 = 0; j4 < CI; j4 += 4) {
            f4 w = *(const f4*)&wrec[t * CI + j4];
            f4 g4 = *(const f4*)&bg[j4];
            a += w[0] * g4[0] + w[1] * g4[1] + w[2] * g4[2] + w[3] * g4[3];
        }
        pv[t] = iv * a;
    } else {
        int tt = t - 256;
        float aw = 0.f, at = 0.f;
        for (int j = 0; j < CI; ++j) {
            aw = fmaf(wphi[j * C + tt], btheta[j], aw);
            at = fmaf(wtheta[j * C + tt], bphi[j], at);
        }
        wtl[tt] = aw;
        tgl[tt] = at;
    }
    __syncthreads();
    // ---- 0b ----
    if (wid < 2) {
        int j = wid * 64 + lane;
        float a = 0.f;
#pragma unroll 4
        for (int c4 = 0; c4 < C; c4 += 4) {
            f4 w = *(const f4*)&wphi[j * C + c4];
            a += w[0] * sl[c4] + w[1] * sl[c4 + 1] + w[2] * sl[c4 + 2] + w[3] * sl[c4 + 3];
        }
        uu[j] = a;
    } else if (wid < 4) {
        int j = (wid - 2) * 64 + lane;
        float a = 0.f;
#pragma unroll 4
        for (int c4 = 0; c4 < C; c4 += 4) {
            f4 w = *(const f4*)&wg[j * C + c4];
            a += w[0] * sl[c4] + w[1] * sl[c4 + 1] + w[2] * sl[c4 + 2] + w[3] * sl[c4 + 3];
        }
        vv[j] = a;
    } else if (wid == 4) {
        float a = sl[lane] * wtl[lane] + sl[lane + 64] * wtl[lane + 64]
                + sl[lane + 128] * wtl[lane + 128] + sl[lane + 192] * wtl[lane + 192];
#pragma unroll
        for (int m = 32; m >= 1; m >>= 1) a += __shfl_xor(a, m, 64);
        if (lane == 0) scal[1] = a;
    } else if (wid == 5) {
        float a = bphi[lane] * btheta[lane] + bphi[lane + 64] * btheta[lane + 64];
#pragma unroll
        for (int m = 32; m >= 1; m >>= 1) a += __shfl_xor(a, m, 64);
        if (lane == 0) scal[0] = a;
    }
    __syncthreads();
    // ---- 0c (consumed after C; intervening barriers order it) ----
    if (t < 256) {
        float a = 0.f;
        for (int j = 0; j < CI; ++j) a = fmaf(uu[j], wtheta[j * C + t], a);
        qarr[t] = a;
    } else {
        int tt = t - 256;
        float a = 0.f;
#pragma unroll 4
        for (int j4 = 0; j4 < CI; j4 += 4) {
            f4 w = *(const f4*)&wrec[tt * CI + j4];
            a += w[0] * vv[j4] + w[1] * vv[j4 + 1] + w[2] * vv[j4 + 2] + w[3] * vv[j4 + 3];
        }
        Ls[tt] = invL[tt] * a;
    }
    // ---- A: Ut[j][c] = (G·Wφᵀ)ᵀ.  M=256(c) x N=128(j), wave 64x64 ----
    {
        int m0 = (wid >> 1) * 64, n0 = (wid & 1) * 64;
        f32x4 acc[4][4] = {};
        const short* Gb = Gbf + (size_t)b * C * C;
        for (int k = 0; k < C; k += 32) {
            short8 av[4], bv[4];
#pragma unroll
            for (int mi = 0; mi < 4; ++mi)
                av[mi] = *(const short8*)(Gb + (size_t)(m0 + mi * 16 + lm) * C + k + lk);
#pragma unroll
            for (int nj = 0; nj < 4; ++nj) {
                const float* w = wphi + (size_t)(n0 + nj * 16 + lm) * C + k + lk;
                bv[nj] = pack8(*(const f4*)w, *(const f4*)(w + 4));
            }
#pragma unroll
            for (int mi = 0; mi < 4; ++mi)
#pragma unroll
                for (int nj = 0; nj < 4; ++nj)
                    acc[mi][nj] = __builtin_amdgcn_mfma_f32_16x16x32_bf16(av[mi], bv[nj], acc[mi][nj], 0, 0, 0);
        }
#pragma unroll
        for (int mi = 0; mi < 4; ++mi)
#pragma unroll
            for (int nj = 0; nj < 4; ++nj)
#pragma unroll
                for (int r = 0; r < 4; ++r)
                    buf1[(n0 + nj * 16 + lm) * 264 + (m0 + mi * 16 + r0q + r)] = f2bf(acc[mi][nj][r]);
    }
    __syncthreads();
    // ---- B: T2t[j][i] = (Wg·U)ᵀ.  M=128(i) x N=128(j), wave 64x32 ----
    {
        int m0 = (wid >> 2) * 64, n0 = (wid & 3) * 32;
        f32x4 acc[4][2] = {};
        for (int k = 0; k < C; k += 32) {
            short8 av[4], bv[2];
#pragma unroll
            for (int mi = 0; mi < 4; ++mi) {
                const float* w = wg + (size_t)(m0 + mi * 16 + lm) * C + k + lk;
                av[mi] = pack8(*(const f4*)w, *(const f4*)(w + 4));
            }
#pragma unroll
            for (int nj = 0; nj < 2; ++nj)
                bv[nj] = *(const short8*)(buf1 + (n0 + nj * 16 + lm) * 264 + k + lk);
#pragma unroll
            for (int mi = 0; mi < 4; ++mi)
#pragma unroll
                for (int nj = 0; nj < 2; ++nj)
                    acc[mi][nj] = __builtin_amdgcn_mfma_f32_16x16x32_bf16(av[mi], bv[nj], acc[mi][nj], 0, 0, 0);
        }
#pragma unroll
        for (int mi = 0; mi < 4; ++mi)
#pragma unroll
            for (int nj = 0; nj < 2; ++nj)
#pragma unroll
                for (int r = 0; r < 4; ++r)
                    buf2[(n0 + nj * 16 + lm) * 136 + (m0 + mi * 16 + r0q + r)] = f2bf(acc[mi][nj][r]);
    }
    __syncthreads();
    // ---- C: T3[o][j] = wrec·T2.  M=256(o) x N=128(j), wave 64x64 ----
    {
        int m0 = (wid >> 1) * 64, n0 = (wid & 1) * 64;
        f32x4 acc[4][4] = {};
        for (int k = 0; k < CI; k += 32) {
            short8 av[4], bv[4];
#pragma unroll
            for (int mi = 0; mi < 4; ++mi) {
                const float* w = wrec + (size_t)(m0 + mi * 16 + lm) * CI + k + lk;
                av[mi] = pack8(*(const f4*)w, *(const f4*)(w + 4));
            }
#pragma unroll
            for (int nj = 0; nj < 4; ++nj)
                bv[nj] = *(const short8*)(buf2 + (n0 + nj * 16 + lm) * 136 + k + lk);
#pragma unroll
            for (int mi = 0; mi < 4; ++mi)
#pragma unroll
                for (int nj = 0; nj < 4; ++nj)
                    acc[mi][nj] = __builtin_amdgcn_mfma_f32_16x16x32_bf16(av[mi], bv[nj], acc[mi][nj], 0, 0, 0);
        }
#pragma unroll
        for (int mi = 0; mi < 4; ++mi)
#pragma unroll
            for (int nj = 0; nj < 4; ++nj)
#pragma unroll
                for (int r = 0; r < 4; ++r)
                    buf1[(m0 + mi * 16 + r0q + r) * 136 + (n0 + nj * 16 + lm)] = f2bf(acc[mi][nj][r]);
    }
    __syncthreads();
    // ---- stage WθT[c'][j] into buf2 ----
    for (int rep = 0; rep < 64; ++rep) {
        int idx = rep * 512 + t;          // 32768 = 128 j x 256 c'
        int j = idx >> 8, cp = idx & 255;
        buf2[cp * 136 + j] = f2bf(wtheta[j * C + cp]);
    }
    __syncthreads();
    // ---- bias5 ----
    if (t < 256) {
        float a = 0.f;
        for (int j = 0; j < CI; ++j) a += bf2f(buf1[t * 136 + j]) * btheta[j];
        bias5[b * C + t] = INVN * invL[t] * a + INVN * scal[1] * pv[t]
                         + scal[0] * (INVN * Ls[t] + pv[t])
                         + invL[t] * brec[t] + beta[t] - mean[t] * invL[t];
    }
    // ---- D: T4 = T3·Wθ + rank-1 → W5bf.  wave 64x128 as two 64x64 reps ----
    short* Wb = W5bf + (size_t)b * C * C;
    for (int rep = 0; rep < 2; ++rep) {
        int m0 = (wid >> 1) * 64, n0 = (wid & 1) * 128 + rep * 64;
        f32x4 acc[4][4] = {};
        for (int k = 0; k < CI; k += 32) {
            short8 av[4], bv[4];
#pragma unroll
            for (int mi = 0; mi < 4; ++mi)
                av[mi] = *(const short8*)(buf1 + (m0 + mi * 16 + lm) * 136 + k + lk);
#pragma unroll
            for (int nj = 0; nj < 4; ++nj)
                bv[nj] = *(const short8*)(buf2 + (n0 + nj * 16 + lm) * 136 + k + lk);
#pragma unroll
            for (int mi = 0; mi < 4; ++mi)
#pragma unroll
                for (int nj = 0; nj < 4; ++nj)
                    acc[mi][nj] = __builtin_amdgcn_mfma_f32_16x16x32_bf16(av[mi], bv[nj], acc[mi][nj], 0, 0, 0);
        }
#pragma unroll
        for (int mi = 0; mi < 4; ++mi) {
#pragma unroll
            for (int r = 0; r < 4; ++r) {
                int o = m0 + mi * 16 + r0q + r;
                float io = invL[o], po = pv[o], ls = Ls[o];
#pragma unroll
                for (int nj = 0; nj < 4; ++nj) {
                    int cp = n0 + nj * 16 + lm;
                    float w5 = INVN * io * acc[mi][nj][r]
                             + po * (INVN * qarr[cp] + tgl[cp])
                             + INVN * ls * tgl[cp];
                    Wb[o * C + cp] = f2bf(w5);
                }
            }
        }
    }
}

// ---- final: out = W5 x + bias5 + x ----
__global__ __launch_bounds__(256) void final_mfma(const float* __restrict__ x,
                                                  const short* __restrict__ W5bf,
                                                  const short* __restrict__ xT,
                                                  const float* __restrict__ bias5,
                                                  float* __restrict__ out) {
    int b = blockIdx.y;
    int n0 = blockIdx.x * 64;
    int tid = threadIdx.x, lane = tid & 63, wid = tid >> 6;
    int obase = wid * 64;
    int lm = lane & 15, lk = (lane >> 4) * 8;
    const short* A0 = W5bf + ((size_t)(b * C) + obase + lm) * C + lk;
    const short* B0 = xT + ((size_t)b * NPIX + n0 + lm) * C + lk;
    f32x4 acc[4][4] = {};
#pragma unroll
    for (int k = 0; k < C; k += 32) {
        short8 a[4], bv[4];
#pragma unroll
        for (int mi = 0; mi < 4; ++mi) a[mi] = *(const short8*)(A0 + mi * 16 * C + k);
#pragma unroll
        for (int nj = 0; nj < 4; ++nj) bv[nj] = *(const short8*)(B0 + nj * 16 * C + k);
#pragma unroll
        for (int mi = 0; mi < 4; ++mi)
#pragma unroll
            for (int nj = 0; nj < 4; ++nj)
                acc[mi][nj] = __builtin_amdgcn_mfma_f32_16x16x32_bf16(a[mi], bv[nj], acc[mi][nj], 0, 0, 0);
    }
    int r0 = (lane >> 4) * 4;
#pragma unroll
    for (int mi = 0; mi < 4; ++mi) {
#pragma unroll
        for (int r = 0; r < 4; ++r) {
            int o = obase + mi * 16 + r0 + r;
            float bias = bias5[b * C + o];
            const float* xrow = x + ((size_t)(b * C + o)) * NPIX;
            float* orow = out + ((size_t)(b * C + o)) * NPIX;
#pragma unroll
            for (int nj = 0; nj < 4; ++nj) {
                int n = n0 + nj * 16 + lm;
                orow[n] = acc[mi][nj][r] + bias + xrow[n];
            }
        }
    }
}

extern "C" void kernel_launch(void* const* d_in, const int* in_sizes, int n_in,
                              void* d_out, int out_size, void* d_ws, size_t ws_size,
                              hipStream_t stream) {
    const float* x       = (const float*)d_in[0];
    const float* w_theta = (const float*)d_in[1];
    const float* b_theta = (const float*)d_in[2];
    const float* w_phi   = (const float*)d_in[3];
    const float* b_phi   = (const float*)d_in[4];
    const float* w_g     = (const float*)d_in[5];
    const float* b_g     = (const float*)d_in[6];
    const float* w_rec   = (const float*)d_in[7];
    const float* b_rec   = (const float*)d_in[8];
    const float* gamma   = (const float*)d_in[9];
    const float* beta    = (const float*)d_in[10];
    const float* mean    = (const float*)d_in[11];
    const float* var     = (const float*)d_in[12];
    float* out = (float*)d_out;

    char* wsb = (char*)d_ws;
    float* spart = (float*)(wsb + 0);             // 4*256*49 f32 = 200704 B
    float* bias5 = (float*)(wsb + 204800);        // 4 KB
    short* Gbf   = (short*)(wsb + (1u << 20));    // 512 KB
    short* W5bf  = (short*)(wsb + (2u << 20));    // 512 KB
    short* xbf   = (short*)(wsb + (4u << 20));    // 6.42 MB
    short* xT    = (short*)(wsb + (12u << 20));   // 6.42 MB

    prep_kernel<<<dim3(49, 4, B), dim3(256), 0, stream>>>(x, xbf, xT, spart);
    xxt_kernel<<<dim3(4, 4, B), dim3(512), 0, stream>>>(xbf, Gbf);
    middle_kernel<<<dim3(B), dim3(512), 139264, stream>>>(
        Gbf, spart, w_rec, w_g, w_phi, w_theta, gamma, var,
        b_g, b_phi, b_theta, b_rec, beta, mean, W5bf, bias5);
    final_mfma<<<dim3(NPIX / 64, B), dim3(256), 0, stream>>>(x, W5bf, xT, bias5, out);
}